// Round 7
// baseline (150.346 us; speedup 1.0000x reference)
//
#include <hip/hip_runtime.h>
#include <hip/hip_bf16.h>

// SubbandCompose R7: 4-way wave split (parity x p-half) at 8 waves/SIMD.
//
// y[t] = X[0] + (-1)^t X[64] + 2*sum_{m=1..63} X[m] cos(pi*m*t/64), t=0..64.
// p = min(t,64-t): E_p = sum_{even m} w_m X[m] c(m,p), O_p = odd-m sum.
//   y[p] = E_p + O_p,  y[64-p] = E_p - O_p.
// out[s,i,j] = (1/512)*sum_{k=0..5} filt[k*64+j]*y[i+5-k][t(k,j)],
//   t(k,j)=j (k even); (j==0?64:64-j) (k odd).
//
// Lesson R2-R6: total waves is the wall (8192 slots; chunked designs only
// made 2224-4448). R7: block=256=4 waves, wave (par,phalf) computes the
// parity-par E/O partial for p-half phalf -> 33 X regs/lane, ~560 FMA, and
// VGPR<=64 so __launch_bounds__(256,8) gives 32 waves/CU (R2's occupancy,
// 1/4 its work). E/O partials via bf16 LDS (R5-proven precision).
// LDS 17152B overlay: X fp32[64][65] -> E,O bf16[64][34] | Ys bf16[64][66].

#define NF 65
#define NT 8192
#define TRUE_LEN 8187
#define FPW 59
#define CPB 139            // chunks per batch element: ceil(8187/59)
#define TSTR 36            // coef table row stride (floats)
#define EOSTR 34           // E/O row stride (bf16) = 17 dwords (odd: 2-way banks)
#define YSTR 66            // Ys row stride (bf16) = 33 dwords

typedef const __attribute__((address_space(4))) float cfloat;
typedef __attribute__((address_space(1))) const void gv_t;
typedef __attribute__((address_space(3))) void lv_t;

__device__ float d_tab[2 * 33 * TSTR];   // [par][p][n], term m = 2n+par

__global__ void build_tab_kernel() {
    int idx = blockIdx.x * 256 + threadIdx.x;
    if (idx >= 2 * 33 * TSTR) return;
    int par = idx / (33 * TSTR);
    int rem = idx - par * 33 * TSTR;
    int p = rem / TSTR, n = rem - p * TSTR;
    int m = 2 * n + par;
    float v = 0.0f;
    if (n < 33 && m <= 64) {
        float w = (m == 0 || m == 64) ? 1.0f : 2.0f;
        int a = (m * p) & 127;                   // cos period 128
        v = w * cospif((float)a * (1.0f / 64.0f));
    }
    d_tab[idx] = v;
}

__device__ __forceinline__ void gl_lds16(const float* g, float* l) {
    __builtin_amdgcn_global_load_lds((gv_t*)g, (lv_t*)l, 16, 0, 0);
}
__device__ __forceinline__ void gl_lds4(const float* g, float* l) {
    __builtin_amdgcn_global_load_lds((gv_t*)g, (lv_t*)l, 4, 0, 0);
}

__global__ __launch_bounds__(256, 8)
void subband_main_kernel(const float* __restrict__ g_in,
                         const float* __restrict__ g_filt,
                         float* __restrict__ g_out)
{
    __shared__ float smem[64 * 67];                              // 17152 B
    __hip_bfloat16* Es = (__hip_bfloat16*)smem;                  // 64x34 @ 0
    __hip_bfloat16* Os = Es + 64 * EOSTR;                        // 64x34 @ 4352
    __hip_bfloat16* Yb = (__hip_bfloat16*)((char*)smem + 8704);  // 64x66 @ 8704

    const int tid  = threadIdx.x;       // 0..255
    const int lane = tid & 63;
    const int wv   = tid >> 6;          // wave role: par = wv&1, phalf = wv>>1
    const int par  = wv & 1;
    const int ph   = wv >> 1;
    const int cg   = blockIdx.x;
    const int s     = cg / CPB;
    const int fbase = (cg - s * CPB) * FPW;

    // ---- stage X rows fbase..fbase+63 (4160 dwords contiguous) via DMA
    if (fbase + 64 <= NT) {
        const float* src = g_in + ((size_t)s * NT + fbase) * NF;
        for (int c = wv; c < 16; c += 4)            // 4 x 1KB chunks per wave
            gl_lds16(src + c * 256 + lane * 4, smem + c * 256);
        if (wv == 0)                                // tail dwords 4096..4159
            gl_lds4(src + 4096 + lane, smem + 4096);
    } else {                                        // clamped edge (16 blocks)
        const float* src = g_in + (size_t)s * NT * NF;
        for (int i = tid; i < 64 * NF; i += 256) {
            int r = i / NF, c = i - r * NF;
            int h = fbase + r; if (h > NT - 1) h = NT - 1;
            smem[i] = src[(size_t)h * NF + c];
        }
    }
    __syncthreads();

    // ---- this wave's parity slice of X: Xr[n] = X[lane][2n+par]
    float Xr[33];
    #pragma unroll
    for (int n = 0; n < 32; ++n) Xr[n] = smem[lane * NF + 2 * n + par];
    Xr[32] = (par == 0) ? smem[lane * NF + 64] : 0.0f;
    __syncthreads();   // X region dead; E/O overlay it

    // ---- stage 1: p-quarter per wave, coefficients via scalar pipe
    {
        const int tbase = __builtin_amdgcn_readfirstlane(
            par * (33 * TSTR) + ph * (17 * TSTR));
        cfloat* ct = (cfloat*)(unsigned long long)(const float*)(d_tab + tbase);
        __hip_bfloat16* eo = (par == 0) ? Es : Os;
        const int pcnt = 17 - ph;                   // 17 or 16
        for (int pp = 0; pp < pcnt; ++pp) {
            cfloat* cf = ct + pp * TSTR;
            float a0 = 0.0f, a1 = 0.0f, a2 = 0.0f, a3 = 0.0f;
            #pragma unroll
            for (int n = 0; n < 32; n += 4) {
                a0 += cf[n]     * Xr[n];
                a1 += cf[n + 1] * Xr[n + 1];
                a2 += cf[n + 2] * Xr[n + 2];
                a3 += cf[n + 3] * Xr[n + 3];
            }
            a0 += cf[32] * Xr[32];                  // O: c[32]=0, Xr[32]=0
            eo[lane * EOSTR + ph * 17 + pp] =
                __float2bfloat16((a0 + a2) + (a1 + a3));
        }
    }
    __syncthreads();

    // ---- combine E/O -> y, pair-packed bf16x2; lane=row, q = wv + 4k
    for (int q = wv; q <= 32; q += 4) {
        const int t0 = 2 * q, t1 = 2 * q + 1;
        const int p0 = (t0 <= 32) ? t0 : 64 - t0;
        const float e0 = __bfloat162float(Es[lane * EOSTR + p0]);
        const float o0 = __bfloat162float(Os[lane * EOSTR + p0]);
        const float y0 = (t0 <= 32) ? e0 + o0 : e0 - o0;
        float y1 = 0.0f;
        if (t1 <= 64) {
            const int p1 = (t1 <= 32) ? t1 : 64 - t1;
            const float e1 = __bfloat162float(Es[lane * EOSTR + p1]);
            const float o1 = __bfloat162float(Os[lane * EOSTR + p1]);
            y1 = (t1 <= 32) ? e1 + o1 : e1 - o1;
        }
        __hip_bfloat162 pk;
        pk.x = __float2bfloat16(y0);
        pk.y = __float2bfloat16(y1);
        *(__hip_bfloat162*)&Yb[lane * YSTR + t0] = pk;
    }
    __syncthreads();

    // ---- stage 2: 6-tap polyphase, rolling window; frames 15/15/15/14
    const int j = lane;
    float fc[6];
    #pragma unroll
    for (int k = 0; k < 6; ++k) fc[k] = g_filt[k * 64 + j] * (1.0f / 512.0f);
    const int te = j;
    const int to = (j == 0) ? 64 : 64 - j;
    const int qlo = wv * 15;
    const int nq  = (wv == 3) ? 14 : 15;

    float we[6], wo[6];
    #pragma unroll
    for (int r = 0; r < 5; ++r) {
        we[r] = __bfloat162float(Yb[(qlo + r) * YSTR + te]);
        wo[r] = __bfloat162float(Yb[(qlo + r) * YSTR + to]);
    }
    float* dst = g_out + ((size_t)s * TRUE_LEN + fbase + qlo) * 64 + j;

    for (int u = 0; u < nq; ++u) {
        if (fbase + qlo + u >= TRUE_LEN) break;
        we[5] = __bfloat162float(Yb[(qlo + u + 5) * YSTR + te]);
        wo[5] = __bfloat162float(Yb[(qlo + u + 5) * YSTR + to]);
        const float o = fc[0] * we[5] + fc[1] * wo[4] + fc[2] * we[3]
                      + fc[3] * wo[2] + fc[4] * we[1] + fc[5] * wo[0];
        dst[(size_t)u * 64] = o;
        #pragma unroll
        for (int r = 0; r < 5; ++r) { we[r] = we[r + 1]; wo[r] = wo[r + 1]; }
    }
}

extern "C" void kernel_launch(void* const* d_in, const int* in_sizes, int n_in,
                              void* d_out, int out_size, void* d_ws, size_t ws_size,
                              hipStream_t stream) {
    const float* g_in   = (const float*)d_in[0];  // (16,1,8192,65) fp32
    const float* g_filt = (const float*)d_in[1];  // (384,) fp32
    float* g_out = (float*)d_out;                 // (16,1,8187*64) fp32

    build_tab_kernel<<<10, 256, 0, stream>>>();   // 2376 entries
    subband_main_kernel<<<16 * CPB, 256, 0, stream>>>(g_in, g_filt, g_out);
}

// Round 8
// 107.518 us; speedup vs baseline: 1.3983x; 1.3983x over previous
//
#include <hip/hip_runtime.h>
#include <hip/hip_bf16.h>

// SubbandCompose R8: R7's 4-way wave split (parity x p-half), with the
// register budget fixed: __launch_bounds__(256,6) -> ~85 VGPR budget, no
// scratch spills (R7's (256,8) forced a 64-reg budget -> allocator collapsed
// to 32 VGPR + spilled everything -> 3x HBM traffic, VALUBusy 18%).
//
// y[t] = X[0] + (-1)^t X[64] + 2*sum_{m=1..63} X[m] cos(pi*m*t/64), t=0..64.
// p = min(t,64-t): E_p = sum_{even m} w_m X[m] c(m,p), O_p = odd-m sum.
//   y[p] = E_p + O_p,  y[64-p] = E_p - O_p.
// out[s,i,j] = (1/512)*sum_{k=0..5} filt[k*64+j]*y[i+5-k][t(k,j)],
//   t(k,j)=j (k even); (j==0?64:64-j) (k odd).
//
// Block = 256 thr = 4 waves = one 64-row chunk (59 frames), 2224 blocks.
// Wave (par,ph): parity-par E/O partial for p-range ph -> 33 X regs/lane,
// ~300 FMA, short s_load chain. E/O partials via bf16 LDS (R5-proven).
// LDS 17152B overlay: X fp32[64][65] -> E,O bf16[64][34] | Ys bf16[64][66].

#define NF 65
#define NT 8192
#define TRUE_LEN 8187
#define FPW 59
#define CPB 139            // chunks per batch element: ceil(8187/59)
#define TSTR 36            // coef table row stride (floats)
#define EOSTR 34           // E/O row stride (bf16) = 17 dwords (odd: 2-way banks)
#define YSTR 66            // Ys row stride (bf16) = 33 dwords

typedef const __attribute__((address_space(4))) float cfloat;
typedef __attribute__((address_space(1))) const void gv_t;
typedef __attribute__((address_space(3))) void lv_t;

__device__ float d_tab[2 * 33 * TSTR];   // [par][p][n], term m = 2n+par

__global__ void build_tab_kernel() {
    int idx = blockIdx.x * 256 + threadIdx.x;
    if (idx >= 2 * 33 * TSTR) return;
    int par = idx / (33 * TSTR);
    int rem = idx - par * 33 * TSTR;
    int p = rem / TSTR, n = rem - p * TSTR;
    int m = 2 * n + par;
    float v = 0.0f;
    if (n < 33 && m <= 64) {
        float w = (m == 0 || m == 64) ? 1.0f : 2.0f;
        int a = (m * p) & 127;                   // cos period 128
        v = w * cospif((float)a * (1.0f / 64.0f));
    }
    d_tab[idx] = v;
}

__device__ __forceinline__ void gl_lds16(const float* g, float* l) {
    __builtin_amdgcn_global_load_lds((gv_t*)g, (lv_t*)l, 16, 0, 0);
}
__device__ __forceinline__ void gl_lds4(const float* g, float* l) {
    __builtin_amdgcn_global_load_lds((gv_t*)g, (lv_t*)l, 4, 0, 0);
}

__global__ __launch_bounds__(256, 6)
void subband_main_kernel(const float* __restrict__ g_in,
                         const float* __restrict__ g_filt,
                         float* __restrict__ g_out)
{
    __shared__ float smem[64 * 67];                              // 17152 B
    __hip_bfloat16* Es = (__hip_bfloat16*)smem;                  // 64x34 @ 0
    __hip_bfloat16* Os = Es + 64 * EOSTR;                        // 64x34 @ 4352
    __hip_bfloat16* Yb = (__hip_bfloat16*)((char*)smem + 8704);  // 64x66 @ 8704

    const int tid  = threadIdx.x;       // 0..255
    const int lane = tid & 63;
    const int wv   = tid >> 6;          // wave role: par = wv&1, phalf = wv>>1
    const int par  = wv & 1;
    const int ph   = wv >> 1;
    const int cg   = blockIdx.x;
    const int s     = cg / CPB;
    const int fbase = (cg - s * CPB) * FPW;

    // ---- stage X rows fbase..fbase+63 (4160 dwords contiguous) via DMA
    if (fbase + 64 <= NT) {
        const float* src = g_in + ((size_t)s * NT + fbase) * NF;
        for (int c = wv; c < 16; c += 4)            // 4 x 1KB chunks per wave
            gl_lds16(src + c * 256 + lane * 4, smem + c * 256);
        if (wv == 0)                                // tail dwords 4096..4159
            gl_lds4(src + 4096 + lane, smem + 4096);
    } else {                                        // clamped edge (16 blocks)
        const float* src = g_in + (size_t)s * NT * NF;
        for (int i = tid; i < 64 * NF; i += 256) {
            int r = i / NF, c = i - r * NF;
            int h = fbase + r; if (h > NT - 1) h = NT - 1;
            smem[i] = src[(size_t)h * NF + c];
        }
    }
    __syncthreads();

    // ---- this wave's parity slice of X: Xr[n] = X[lane][2n+par]
    float Xr[33];
    #pragma unroll
    for (int n = 0; n < 32; ++n) Xr[n] = smem[lane * NF + 2 * n + par];
    Xr[32] = (par == 0) ? smem[lane * NF + 64] : 0.0f;
    __syncthreads();   // X region dead; E/O overlay it

    // ---- stage 1: p-quarter per wave, coefficients via scalar pipe
    {
        const int tbase = __builtin_amdgcn_readfirstlane(
            par * (33 * TSTR) + ph * (17 * TSTR));
        cfloat* ct = (cfloat*)(unsigned long long)(const float*)(d_tab + tbase);
        __hip_bfloat16* eo = (par == 0) ? Es : Os;
        const int pcnt = 17 - ph;                   // 17 or 16
        for (int pp = 0; pp < pcnt; ++pp) {
            cfloat* cf = ct + pp * TSTR;
            float a0 = 0.0f, a1 = 0.0f, a2 = 0.0f, a3 = 0.0f;
            #pragma unroll
            for (int n = 0; n < 32; n += 4) {
                a0 += cf[n]     * Xr[n];
                a1 += cf[n + 1] * Xr[n + 1];
                a2 += cf[n + 2] * Xr[n + 2];
                a3 += cf[n + 3] * Xr[n + 3];
            }
            a0 += cf[32] * Xr[32];                  // O: c[32]=0, Xr[32]=0
            eo[lane * EOSTR + ph * 17 + pp] =
                __float2bfloat16((a0 + a2) + (a1 + a3));
        }
    }
    __syncthreads();

    // ---- combine E/O -> y, pair-packed bf16x2; lane=row, q = wv + 4k
    for (int q = wv; q <= 32; q += 4) {
        const int t0 = 2 * q, t1 = 2 * q + 1;
        const int p0 = (t0 <= 32) ? t0 : 64 - t0;
        const float e0 = __bfloat162float(Es[lane * EOSTR + p0]);
        const float o0 = __bfloat162float(Os[lane * EOSTR + p0]);
        const float y0 = (t0 <= 32) ? e0 + o0 : e0 - o0;
        float y1 = 0.0f;
        if (t1 <= 64) {
            const int p1 = (t1 <= 32) ? t1 : 64 - t1;
            const float e1 = __bfloat162float(Es[lane * EOSTR + p1]);
            const float o1 = __bfloat162float(Os[lane * EOSTR + p1]);
            y1 = (t1 <= 32) ? e1 + o1 : e1 - o1;
        }
        __hip_bfloat162 pk;
        pk.x = __float2bfloat16(y0);
        pk.y = __float2bfloat16(y1);
        *(__hip_bfloat162*)&Yb[lane * YSTR + t0] = pk;
    }
    __syncthreads();

    // ---- stage 2: 6-tap polyphase, rolling window; frames 15/15/15/14
    const int j = lane;
    float fc[6];
    #pragma unroll
    for (int k = 0; k < 6; ++k) fc[k] = g_filt[k * 64 + j] * (1.0f / 512.0f);
    const int te = j;
    const int to = (j == 0) ? 64 : 64 - j;
    const int qlo = wv * 15;
    const int nq  = (wv == 3) ? 14 : 15;

    float we[6], wo[6];
    #pragma unroll
    for (int r = 0; r < 5; ++r) {
        we[r] = __bfloat162float(Yb[(qlo + r) * YSTR + te]);
        wo[r] = __bfloat162float(Yb[(qlo + r) * YSTR + to]);
    }
    float* dst = g_out + ((size_t)s * TRUE_LEN + fbase + qlo) * 64 + j;

    for (int u = 0; u < nq; ++u) {
        if (fbase + qlo + u >= TRUE_LEN) break;
        we[5] = __bfloat162float(Yb[(qlo + u + 5) * YSTR + te]);
        wo[5] = __bfloat162float(Yb[(qlo + u + 5) * YSTR + to]);
        const float o = fc[0] * we[5] + fc[1] * wo[4] + fc[2] * we[3]
                      + fc[3] * wo[2] + fc[4] * we[1] + fc[5] * wo[0];
        dst[(size_t)u * 64] = o;
        #pragma unroll
        for (int r = 0; r < 5; ++r) { we[r] = we[r + 1]; wo[r] = wo[r + 1]; }
    }
}

extern "C" void kernel_launch(void* const* d_in, const int* in_sizes, int n_in,
                              void* d_out, int out_size, void* d_ws, size_t ws_size,
                              hipStream_t stream) {
    const float* g_in   = (const float*)d_in[0];  // (16,1,8192,65) fp32
    const float* g_filt = (const float*)d_in[1];  // (384,) fp32
    float* g_out = (float*)d_out;                 // (16,1,8187*64) fp32

    build_tab_kernel<<<10, 256, 0, stream>>>();   // 2376 entries
    subband_main_kernel<<<16 * CPB, 256, 0, stream>>>(g_in, g_filt, g_out);
}